// Round 3
// baseline (748.975 us; speedup 1.0000x reference)
//
#include <hip/hip_runtime.h>
#include <math.h>

#define C_IN 32
#define C2C 64
#define HH 256
#define WW 256

#define R2 0.70710678118654752f

// Branchless gelu: erf via Abramowitz-Stegun 7.1.26 (|eps| <= 1.5e-7), hw rcp/exp.
__device__ __forceinline__ float gelu_f(float x) {
    float u = x * R2;
    float a = fabsf(u);
    float t = __builtin_amdgcn_rcpf(fmaf(0.3275911f, a, 1.0f));
    float p = t * fmaf(t, fmaf(t, fmaf(t, fmaf(t, 1.061405429f, -1.453152027f),
                                       1.421413741f), -0.284496736f), 0.254829592f);
    float e = __expf(-a * a);
    float er = fmaf(-p, e, 1.0f);
    er = copysignf(er, u);
    return 0.5f * x * (1.0f + er);
}

// cos/sin(2*pi*l/8) for the inverse-DFT rotation seed (2 loads per thread, once)
__device__ const float CT8d[8] = {1.0f, R2, 0.0f, -R2, -1.0f, -R2, 0.0f, R2};
__device__ const float ST8d[8] = {0.0f, R2, 1.0f, R2, 0.0f, -R2, -1.0f, -R2};

// 8-point real DFT over h with conjugate symmetry: outputs u=0..4 (Ai[0]=Ai[4]=0).
__device__ __forceinline__ void rdft8(const float t[8], float Ar[5], float Ai[5]) {
    float e0 = t[0] + t[4], e1 = t[1] + t[5], e2 = t[2] + t[6], e3 = t[3] + t[7];
    float s04 = t[0] - t[4], s26 = t[2] - t[6];
    float am = t[1] - t[3] - t[5] + t[7];
    float bm = t[1] + t[3] - t[5] - t[7];
    float e02 = e0 + e2, e13 = e1 + e3;
    Ar[0] = e02 + e13;
    Ar[4] = e02 - e13;
    Ar[2] = e0 - e2;
    Ai[2] = e3 - e1;
    float ma = R2 * am, mb = R2 * bm;
    Ar[1] = s04 + ma;
    Ar[3] = s04 - ma;
    Ai[1] = -s26 - mb;
    Ai[3] = s26 - mb;
    Ai[0] = 0.f;
    Ai[4] = 0.f;
}

// Store only spectral rows u=0..4 (conjugate symmetry); stride 44 per channel.
// Ar at c2*44 + u*8 + w ; Ai at 2816 + same.
__device__ __forceinline__ void wrA5(float* ubuf, int c2x, int l,
                                     const float Ar[5], const float Ai[5]) {
    float* pr = &ubuf[c2x * 44 + l];
    float* pi = &ubuf[2816 + c2x * 44 + l];
    pr[0]  = Ar[0];  pi[0]  = 0.f;
    pr[8]  = Ar[1];  pi[8]  = Ai[1];
    pr[16] = Ar[2];  pi[16] = Ai[2];
    pr[24] = Ar[3];  pi[24] = Ai[3];
    pr[32] = Ar[4];  pi[32] = 0.f;
}

// column DFT (v=0..4) + fft1 * -> gelu -> * fft2 ; row u=l via A[u]=conj(A[8-u])
__device__ __forceinline__ void colpass(const float* ubuf, int c2x, int l,
                                        const float* __restrict__ fft1,
                                        const float* __restrict__ fft2,
                                        float gr[5], float gi[5]) {
    constexpr float CT[8] = {1.0f, R2, 0.0f, -R2, -1.0f, -R2, 0.0f, R2};
    constexpr float ST[8] = {0.0f, R2, 1.0f, R2, 0.0f, -R2, -1.0f, -R2};
    const int row = (l <= 4) ? l : 8 - l;
    const float sgn = (l <= 4) ? 1.0f : -1.0f;
    float Ar2[8], Ai2[8];
    {
        const float4 r0 = *(const float4*)&ubuf[c2x * 44 + row * 8];
        const float4 r1 = *(const float4*)&ubuf[c2x * 44 + row * 8 + 4];
        const float4 i0 = *(const float4*)&ubuf[2816 + c2x * 44 + row * 8];
        const float4 i1 = *(const float4*)&ubuf[2816 + c2x * 44 + row * 8 + 4];
        Ar2[0] = r0.x; Ar2[1] = r0.y; Ar2[2] = r0.z; Ar2[3] = r0.w;
        Ar2[4] = r1.x; Ar2[5] = r1.y; Ar2[6] = r1.z; Ar2[7] = r1.w;
        Ai2[0] = sgn * i0.x; Ai2[1] = sgn * i0.y; Ai2[2] = sgn * i0.z; Ai2[3] = sgn * i0.w;
        Ai2[4] = sgn * i1.x; Ai2[5] = sgn * i1.y; Ai2[6] = sgn * i1.z; Ai2[7] = sgn * i1.w;
    }
    #pragma unroll
    for (int v = 0; v < 5; ++v) {
        float fr = 0.f, fi = 0.f;
        #pragma unroll
        for (int w = 0; w < 8; ++w) {
            const int k = (v * w) & 7;
            fr += Ar2[w] * CT[k] + Ai2[w] * ST[k];
            fi += Ai2[w] * CT[k] - Ar2[w] * ST[k];
        }
        const float s1 = fft1[(c2x * 8 + l) * 5 + v];
        const float s2 = fft2[(c2x * 8 + l) * 5 + v];
        gr[v] = gelu_f(fr * s1) * s2;
        gi[v] = gelu_f(fi * s1) * s2;
    }
}

// inverse: row-iDFT over u via rotation recurrence, then column-iDFT (hermitian over v)
__device__ __forceinline__ void invpass(const float* gtab, float c1, float s1, float o[8]) {
    constexpr float CT[8] = {1.0f, R2, 0.0f, -R2, -1.0f, -R2, 0.0f, R2};
    constexpr float ST[8] = {0.0f, R2, 1.0f, R2, 0.0f, -R2, -1.0f, -R2};
    float Rr[5] = {0.f, 0.f, 0.f, 0.f, 0.f};
    float Ri[5] = {0.f, 0.f, 0.f, 0.f, 0.f};
    float cu = 1.f, su = 0.f;
    #pragma unroll
    for (int u = 0; u < 8; ++u) {
        const float4 g0 = *(const float4*)&gtab[u * 12];
        const float4 g1 = *(const float4*)&gtab[u * 12 + 4];
        const float2 g2 = *(const float2*)&gtab[u * 12 + 8];
        Rr[0] += g0.x * cu - g0.y * su;  Ri[0] += g0.x * su + g0.y * cu;
        Rr[1] += g0.z * cu - g0.w * su;  Ri[1] += g0.z * su + g0.w * cu;
        Rr[2] += g1.x * cu - g1.y * su;  Ri[2] += g1.x * su + g1.y * cu;
        Rr[3] += g1.z * cu - g1.w * su;  Ri[3] += g1.z * su + g1.w * cu;
        Rr[4] += g2.x * cu - g2.y * su;  Ri[4] += g2.x * su + g2.y * cu;
        const float nc = cu * c1 - su * s1;
        su = cu * s1 + su * c1;
        cu = nc;
    }
    #pragma unroll
    for (int w = 0; w < 8; ++w) {
        float s = 0.f;
        #pragma unroll
        for (int v = 0; v < 5; ++v) {
            const float m = (v == 0 || v == 4) ? 1.0f : 2.0f;
            const int k = (v * w) & 7;
            s += m * (Rr[v] * CT[k] - Ri[v] * ST[k]);
        }
        o[w] = s * 0.015625f;
    }
}

// ---------------------------------------------------------------------------
// K1: 1x1 conv in (32->64) + per-patch rfft2*fft1 -> gelu -> *fft2 -> irfft2
// 256 threads per patch; thread = (c2 in 0..31 owning {c2, c2+32}, l = 0..7)
// z is written PATCH-LOCAL: [b][c2][hp][wp][h][w] -> 256B contiguous per patch
// (full-line coalesced writes; kills partial-line RMW fetch seen in rocprof)
// ---------------------------------------------------------------------------
__global__ __launch_bounds__(256, 6)
void k1_spectral(const float* __restrict__ x, const float* __restrict__ w_in,
                 const float* __restrict__ b_in, const float* __restrict__ fft1,
                 const float* __restrict__ fft2, float* __restrict__ z)
{
    // union buffer (25600 B -> 6 blocks/CU):
    //  phase0: xs[c][w][h] at c*100+w*12+h (0..3199); lw2 pairs at 3200+c*66+...
    //  phase1: Ar rows 0..4 at c2*44+u*8+w; Ai at 2816+... (0..5631)
    //  phase2: g at c2*100+u*12+2v (0..6399)
    __shared__ __align__(16) float ubuf[6400];

    const int tid = threadIdx.x;
    const int c2 = tid >> 3;
    const int l  = tid & 7;

    // XCD-bijective swizzle: each XCD gets one contiguous batch image (1024 blocks)
    int Lf = blockIdx.x + (blockIdx.y << 5) + (blockIdx.z << 10);
    int Lp = ((Lf & 7) << 10) | (Lf >> 3);
    const int b  = Lp >> 10;
    const int hp = (Lp >> 5) & 31;
    const int wp = Lp & 31;
    const int h0 = hp << 3, w0 = wp << 3;

    // ---- stage x patch (f4 global loads) and w_in pairs ----
    #pragma unroll
    for (int k = 0; k < 2; ++k) {
        int i = tid + (k << 8);               // 0..511 float4s
        int c = i >> 4, rem = i & 15;
        int h = rem >> 1, half = rem & 1;
        const float4 v = *(const float4*)&x[((b * C_IN + c) * HH + h0 + h) * WW + w0 + (half << 2)];
        int base = c * 100 + half * 48 + h;
        ubuf[base]      = v.x;
        ubuf[base + 12] = v.y;
        ubuf[base + 24] = v.z;
        ubuf[base + 36] = v.w;
    }
    #pragma unroll
    for (int k = 0; k < 2; ++k) {
        int i = tid + (k << 8);               // 0..511 float4s over w_in
        int ci = i >> 3, c4 = (i & 7) << 2;
        const float4 v = *(const float4*)&w_in[ci * C_IN + c4];
        int col = ((ci & 31) << 1) | (ci >> 5);
        ubuf[3200 + (c4 + 0) * 66 + col] = v.x;
        ubuf[3200 + (c4 + 1) * 66 + col] = v.y;
        ubuf[3200 + (c4 + 2) * 66 + col] = v.z;
        ubuf[3200 + (c4 + 3) * 66 + col] = v.w;
    }
    __syncthreads();

    // ---- 1x1 conv: column w=l, 2 channels per thread ----
    float t0[8], t1[8];
    {
        const float bv0 = b_in[c2], bv1 = b_in[c2 + 32];
        #pragma unroll
        for (int h = 0; h < 8; ++h) { t0[h] = bv0; t1[h] = bv1; }
        #pragma unroll
        for (int c = 0; c < C_IN; ++c) {
            const float2 wv = *(const float2*)&ubuf[3200 + c * 66 + (c2 << 1)];
            const float4 xa = *(const float4*)&ubuf[c * 100 + l * 12];
            const float4 xb = *(const float4*)&ubuf[c * 100 + l * 12 + 4];
            float xv[8];
            xv[0] = xa.x; xv[1] = xa.y; xv[2] = xa.z; xv[3] = xa.w;
            xv[4] = xb.x; xv[5] = xb.y; xv[6] = xb.z; xv[7] = xb.w;
            #pragma unroll
            for (int h = 0; h < 8; ++h) {
                t0[h] = fmaf(wv.x, xv[h], t0[h]);
                t1[h] = fmaf(wv.y, xv[h], t1[h]);
            }
        }
    }

    // ---- row DFT over h (symmetry-reduced) ----
    float Ar_a[5], Ai_a[5], Ar_b[5], Ai_b[5];
    rdft8(t0, Ar_a, Ai_a);
    rdft8(t1, Ar_b, Ai_b);
    __syncthreads();            // xs/lw2 dead -> reuse for A
    wrA5(ubuf, c2,      l, Ar_a, Ai_a);
    wrA5(ubuf, c2 + 32, l, Ar_b, Ai_b);
    __syncthreads();

    // ---- column DFT + filter + gelu (role u = l) ----
    float gr_a[5], gi_a[5], gr_b[5], gi_b[5];
    colpass(ubuf, c2,      l, fft1, fft2, gr_a, gi_a);
    colpass(ubuf, c2 + 32, l, fft1, fft2, gr_b, gi_b);
    __syncthreads();            // A dead -> reuse for g
    {
        int gb = c2 * 100 + l * 12;
        *(float4*)&ubuf[gb]     = make_float4(gr_a[0], gi_a[0], gr_a[1], gi_a[1]);
        *(float4*)&ubuf[gb + 4] = make_float4(gr_a[2], gi_a[2], gr_a[3], gi_a[3]);
        *(float2*)&ubuf[gb + 8] = make_float2(gr_a[4], gi_a[4]);
        gb = (c2 + 32) * 100 + l * 12;
        *(float4*)&ubuf[gb]     = make_float4(gr_b[0], gi_b[0], gr_b[1], gi_b[1]);
        *(float4*)&ubuf[gb + 4] = make_float4(gr_b[2], gi_b[2], gr_b[3], gi_b[3]);
        *(float2*)&ubuf[gb + 8] = make_float2(gr_b[4], gi_b[4]);
    }
    __syncthreads();

    // ---- inverse (role h = l), rotation recurrence twiddles ----
    const float c1 = CT8d[l], s1 = ST8d[l];
    float o[8];
    const int pbase = (((b * C2C) * 1024) + hp * 32 + wp) << 6;   // word idx of patch (c2=0)
    invpass(&ubuf[c2 * 100], c1, s1, o);
    {
        float* zp = &z[pbase + (c2 << 16) + (l << 3)];
        *(float4*)&zp[0] = make_float4(o[0], o[1], o[2], o[3]);
        *(float4*)&zp[4] = make_float4(o[4], o[5], o[6], o[7]);
    }
    invpass(&ubuf[(c2 + 32) * 100], c1, s1, o);
    {
        float* zp = &z[pbase + ((c2 + 32) << 16) + (l << 3)];
        *(float4*)&zp[0] = make_float4(o[0], o[1], o[2], o[3]);
        *(float4*)&zp[4] = make_float4(o[4], o[5], o[6], o[7]);
    }
}

// ---------------------------------------------------------------------------
// K2: 7x7 depthwise conv (pad 3) + gelu + 1x1 conv out (64->32) + bias
// 16x16 tile per 256-thread WG; 16 chunks of 4 channels (one per wave).
// Conflict-free LDS: row stride 32 words + 16B-slot XOR swizzle (slot ^= row&7);
// dw lane roles remapped (bx=lane>>4, oy=lane&15) so each 8-lane group covers
// 8 consecutive rows at one x-slot -> 8 distinct bank-slots per b128.
// ---------------------------------------------------------------------------
__global__ __launch_bounds__(256, 6)
void k2_dwconv(const float* __restrict__ z, const float* __restrict__ w_dw,
               const float* __restrict__ b_dw, const float* __restrict__ w_out,
               const float* __restrict__ b_out, float* __restrict__ out)
{
    __shared__ __align__(16) float zs[4 * 22 * 32];   // 11264 B, swizzled slots
    __shared__ __align__(16) float gbuf[4 * 16 * 32]; // 8192 B, swizzled slots

    const int tid = threadIdx.x;

    // XCD-bijective swizzle (2048 blocks, one image per XCD)
    int L = blockIdx.x + (blockIdx.y << 4) + (blockIdx.z << 8);
    int Lp = ((L & 7) << 8) | (L >> 3);
    const int b  = Lp >> 8;
    const int ty = (Lp >> 4) & 15;
    const int tx = Lp & 15;
    const int x0g = tx << 4, y0g = ty << 4;

    // dw roles: wave = channel; lane -> (x-quad bx, output row oy)
    const int lane = tid & 63;
    const int wv   = tid >> 6;              // 0..3
    const int bx   = lane >> 4;             // 0..3 (x block, 4 wide)
    const int oy   = lane & 15;             // 0..15 output row

    // fold / output roles: thread = pixel
    const int ox = tid & 15, py = tid >> 4;

    float acc[32];
    #pragma unroll
    for (int c = 0; c < 32; ++c) acc[c] = b_out[c];

    for (int chunk = 0; chunk < 16; ++chunk) {
        const int cbase = chunk << 2;
        __syncthreads();   // protect zs/gbuf from previous iteration's readers

        // ---- stage 4 channels, 22-row x 24-col halo window (patch-local z) ----
        // window cols x0g-4 .. x0g+19 (4-aligned); rows y0g-3 .. y0g+18
        for (int i = tid; i < 528; i += 256) {     // 4 ch * 22 rows * 6 f4
            int c2l = i / 132;
            int r   = i - c2l * 132;
            int yy  = r / 6;
            int x4  = r - yy * 6;
            int gy = y0g - 3 + yy;
            int gx = x0g - 4 + (x4 << 2);
            float4 v = make_float4(0.f, 0.f, 0.f, 0.f);
            if ((unsigned)gy < HH && (unsigned)gx < WW) {
                const int hp = gy >> 3, wpp = gx >> 3;
                const int off = ((gy & 7) << 3) | (gx & 7);
                v = *(const float4*)&z[(((b * C2C + cbase + c2l) * 1024 + hp * 32 + wpp) << 6) + off];
            }
            *(float4*)&zs[c2l * 704 + yy * 32 + ((x4 ^ (yy & 7)) << 2)] = v;
        }
        __syncthreads();

        // ---- depthwise 7x7 for channel cbase+wv: 4 outputs per lane ----
        {
            const int c2u = __builtin_amdgcn_readfirstlane(cbase + wv);
            const float* wd = &w_dw[c2u * 49];        // uniform -> s_loads
            const float bd = b_dw[c2u];
            float a0 = bd, a1 = bd, a2 = bd, a3 = bd;
            const float* zch = &zs[wv * 704];
            #pragma unroll
            for (int ky = 0; ky < 7; ++ky) {
                const int row = oy + ky;
                const int rs = row & 7;
                const float* zr = &zch[row * 32];
                const float4 q0 = *(const float4*)&zr[((bx ^ rs) << 2)];
                const float4 q1 = *(const float4*)&zr[(((bx + 1) ^ rs) << 2)];
                const float4 q2 = *(const float4*)&zr[(((bx + 2) ^ rs) << 2)];
                const float fv[11] = {q0.x, q0.y, q0.z, q0.w, q1.x, q1.y, q1.z, q1.w,
                                      q2.x, q2.y, q2.z};
                #pragma unroll
                for (int kx = 0; kx < 7; ++kx) {
                    const float w = wd[ky * 7 + kx];
                    a0 = fmaf(w, fv[kx + 1], a0);
                    a1 = fmaf(w, fv[kx + 2], a1);
                    a2 = fmaf(w, fv[kx + 3], a2);
                    a3 = fmaf(w, fv[kx + 4], a3);
                }
            }
            *(float4*)&gbuf[wv * 512 + oy * 32 + ((bx ^ (oy & 7)) << 2)] =
                make_float4(gelu_f(a0), gelu_f(a1), gelu_f(a2), gelu_f(a3));
        }
        __syncthreads();

        // ---- fold chunk into 32 output-channel accumulators (uniform w_out) ----
        {
            const int sw = (((ox >> 2) ^ (py & 7)) << 2) | (ox & 3);
            #pragma unroll
            for (int cc = 0; cc < 4; ++cc) {
                const float gv = gbuf[cc * 512 + py * 32 + sw];
                const int c2i = cbase + cc;
                #pragma unroll
                for (int c = 0; c < 32; ++c)
                    acc[c] = fmaf(w_out[c * C2C + c2i], gv, acc[c]);
            }
        }
    }

    #pragma unroll
    for (int c = 0; c < 32; ++c)
        out[((b * C_IN + c) * HH + y0g + py) * WW + x0g + ox] = acc[c];
}

extern "C" void kernel_launch(void* const* d_in, const int* in_sizes, int n_in,
                              void* d_out, int out_size, void* d_ws, size_t ws_size,
                              hipStream_t stream) {
    const float* x     = (const float*)d_in[0];
    const float* w_in  = (const float*)d_in[1];
    const float* b_in  = (const float*)d_in[2];
    const float* fft1  = (const float*)d_in[3];
    const float* fft2  = (const float*)d_in[4];
    const float* w_dw  = (const float*)d_in[5];
    const float* b_dw  = (const float*)d_in[6];
    const float* w_out = (const float*)d_in[7];
    const float* b_out = (const float*)d_in[8];
    float* outp = (float*)d_out;
    float* z = (float*)d_ws;   // 128 MiB intermediate, patch-local [b][c2][hp][wp][8][8]

    dim3 g1(32, 32, 8);
    k1_spectral<<<g1, 256, 0, stream>>>(x, w_in, b_in, fft1, fft2, z);
    dim3 g2(16, 16, 8);
    k2_dwconv<<<g2, 256, 0, stream>>>(z, w_dw, b_dw, w_out, b_out, outp);
}

// Round 4
// 378.381 us; speedup vs baseline: 1.9794x; 1.9794x over previous
//
#include <hip/hip_runtime.h>
#include <math.h>

#define C_IN 32
#define C2C 64
#define HH 256
#define WW 256

#define R2 0.70710678118654752f

// Branchless gelu: erf via Abramowitz-Stegun 7.1.26 (|eps| <= 1.5e-7), hw rcp/exp.
__device__ __forceinline__ float gelu_f(float x) {
    float u = x * R2;
    float a = fabsf(u);
    float t = __builtin_amdgcn_rcpf(fmaf(0.3275911f, a, 1.0f));
    float p = t * fmaf(t, fmaf(t, fmaf(t, fmaf(t, 1.061405429f, -1.453152027f),
                                       1.421413741f), -0.284496736f), 0.254829592f);
    float e = __expf(-a * a);
    float er = fmaf(-p, e, 1.0f);
    er = copysignf(er, u);
    return 0.5f * x * (1.0f + er);
}

// cos/sin(2*pi*l/8) for the inverse-DFT rotation seed (2 loads per thread, once)
__device__ const float CT8d[8] = {1.0f, R2, 0.0f, -R2, -1.0f, -R2, 0.0f, R2};
__device__ const float ST8d[8] = {0.0f, R2, 1.0f, R2, 0.0f, -R2, -1.0f, -R2};

// 8-point real DFT over h with conjugate symmetry: outputs u=0..4 (Ai[0]=Ai[4]=0).
__device__ __forceinline__ void rdft8(const float t[8], float Ar[5], float Ai[5]) {
    float e0 = t[0] + t[4], e1 = t[1] + t[5], e2 = t[2] + t[6], e3 = t[3] + t[7];
    float s04 = t[0] - t[4], s26 = t[2] - t[6];
    float am = t[1] - t[3] - t[5] + t[7];
    float bm = t[1] + t[3] - t[5] - t[7];
    float e02 = e0 + e2, e13 = e1 + e3;
    Ar[0] = e02 + e13;
    Ar[4] = e02 - e13;
    Ar[2] = e0 - e2;
    Ai[2] = e3 - e1;
    float ma = R2 * am, mb = R2 * bm;
    Ar[1] = s04 + ma;
    Ar[3] = s04 - ma;
    Ai[1] = -s26 - mb;
    Ai[3] = s26 - mb;
    Ai[0] = 0.f;
    Ai[4] = 0.f;
}

// Store only spectral rows u=0..4 (conjugate symmetry); stride 44 per channel.
// Ar at c2*44 + u*8 + w ; Ai at 2816 + same.
__device__ __forceinline__ void wrA5(float* ubuf, int c2x, int l,
                                     const float Ar[5], const float Ai[5]) {
    float* pr = &ubuf[c2x * 44 + l];
    float* pi = &ubuf[2816 + c2x * 44 + l];
    pr[0]  = Ar[0];  pi[0]  = 0.f;
    pr[8]  = Ar[1];  pi[8]  = Ai[1];
    pr[16] = Ar[2];  pi[16] = Ai[2];
    pr[24] = Ar[3];  pi[24] = Ai[3];
    pr[32] = Ar[4];  pi[32] = 0.f;
}

// column DFT (v=0..4) + fft1 * -> gelu -> * fft2 ; row u=l via A[u]=conj(A[8-u])
__device__ __forceinline__ void colpass(const float* ubuf, int c2x, int l,
                                        const float* __restrict__ fft1,
                                        const float* __restrict__ fft2,
                                        float gr[5], float gi[5]) {
    constexpr float CT[8] = {1.0f, R2, 0.0f, -R2, -1.0f, -R2, 0.0f, R2};
    constexpr float ST[8] = {0.0f, R2, 1.0f, R2, 0.0f, -R2, -1.0f, -R2};
    const int row = (l <= 4) ? l : 8 - l;
    const float sgn = (l <= 4) ? 1.0f : -1.0f;
    float Ar2[8], Ai2[8];
    {
        const float4 r0 = *(const float4*)&ubuf[c2x * 44 + row * 8];
        const float4 r1 = *(const float4*)&ubuf[c2x * 44 + row * 8 + 4];
        const float4 i0 = *(const float4*)&ubuf[2816 + c2x * 44 + row * 8];
        const float4 i1 = *(const float4*)&ubuf[2816 + c2x * 44 + row * 8 + 4];
        Ar2[0] = r0.x; Ar2[1] = r0.y; Ar2[2] = r0.z; Ar2[3] = r0.w;
        Ar2[4] = r1.x; Ar2[5] = r1.y; Ar2[6] = r1.z; Ar2[7] = r1.w;
        Ai2[0] = sgn * i0.x; Ai2[1] = sgn * i0.y; Ai2[2] = sgn * i0.z; Ai2[3] = sgn * i0.w;
        Ai2[4] = sgn * i1.x; Ai2[5] = sgn * i1.y; Ai2[6] = sgn * i1.z; Ai2[7] = sgn * i1.w;
    }
    #pragma unroll
    for (int v = 0; v < 5; ++v) {
        float fr = 0.f, fi = 0.f;
        #pragma unroll
        for (int w = 0; w < 8; ++w) {
            const int k = (v * w) & 7;
            fr += Ar2[w] * CT[k] + Ai2[w] * ST[k];
            fi += Ai2[w] * CT[k] - Ar2[w] * ST[k];
        }
        const float s1 = fft1[(c2x * 8 + l) * 5 + v];
        const float s2 = fft2[(c2x * 8 + l) * 5 + v];
        gr[v] = gelu_f(fr * s1) * s2;
        gi[v] = gelu_f(fi * s1) * s2;
    }
}

// inverse: row-iDFT over u via rotation recurrence, then column-iDFT (hermitian over v)
__device__ __forceinline__ void invpass(const float* gtab, float c1, float s1, float o[8]) {
    constexpr float CT[8] = {1.0f, R2, 0.0f, -R2, -1.0f, -R2, 0.0f, R2};
    constexpr float ST[8] = {0.0f, R2, 1.0f, R2, 0.0f, -R2, -1.0f, -R2};
    float Rr[5] = {0.f, 0.f, 0.f, 0.f, 0.f};
    float Ri[5] = {0.f, 0.f, 0.f, 0.f, 0.f};
    float cu = 1.f, su = 0.f;
    #pragma unroll
    for (int u = 0; u < 8; ++u) {
        const float4 g0 = *(const float4*)&gtab[u * 12];
        const float4 g1 = *(const float4*)&gtab[u * 12 + 4];
        const float2 g2 = *(const float2*)&gtab[u * 12 + 8];
        Rr[0] += g0.x * cu - g0.y * su;  Ri[0] += g0.x * su + g0.y * cu;
        Rr[1] += g0.z * cu - g0.w * su;  Ri[1] += g0.z * su + g0.w * cu;
        Rr[2] += g1.x * cu - g1.y * su;  Ri[2] += g1.x * su + g1.y * cu;
        Rr[3] += g1.z * cu - g1.w * su;  Ri[3] += g1.z * su + g1.w * cu;
        Rr[4] += g2.x * cu - g2.y * su;  Ri[4] += g2.x * su + g2.y * cu;
        const float nc = cu * c1 - su * s1;
        su = cu * s1 + su * c1;
        cu = nc;
    }
    #pragma unroll
    for (int w = 0; w < 8; ++w) {
        float s = 0.f;
        #pragma unroll
        for (int v = 0; v < 5; ++v) {
            const float m = (v == 0 || v == 4) ? 1.0f : 2.0f;
            const int k = (v * w) & 7;
            s += m * (Rr[v] * CT[k] - Ri[v] * ST[k]);
        }
        o[w] = s * 0.015625f;
    }
}

// ---------------------------------------------------------------------------
// K1: 1x1 conv in (32->64) + per-patch rfft2*fft1 -> gelu -> *fft2 -> irfft2
// 256 threads per patch; thread = (c2 in 0..31 owning {c2, c2+32}, l = 0..7)
// z is written PATCH-LOCAL: [b][c2][hp][wp][h][w] -> 256B contiguous per patch.
// launch_bounds(256,4): VGPR cap 128. (256,6) capped at ~85 and spilled ->
// 1.35 GB scratch writes, 2.4x slowdown (round-3 post-mortem).
// ---------------------------------------------------------------------------
__global__ __launch_bounds__(256, 4)
void k1_spectral(const float* __restrict__ x, const float* __restrict__ w_in,
                 const float* __restrict__ b_in, const float* __restrict__ fft1,
                 const float* __restrict__ fft2, float* __restrict__ z)
{
    // union buffer (25600 B):
    //  phase0: xs[c][w][h] at c*100+w*12+h (0..3199); lw2 pairs at 3200+c*66+...
    //  phase1: Ar rows 0..4 at c2*44+u*8+w; Ai at 2816+... (0..5631)
    //  phase2: g at c2*100+u*12+2v (0..6399)
    __shared__ __align__(16) float ubuf[6400];

    const int tid = threadIdx.x;
    const int c2 = tid >> 3;
    const int l  = tid & 7;

    // XCD-bijective swizzle: each XCD gets one contiguous batch image (8192 blocks)
    int Lf = blockIdx.x + (blockIdx.y << 5) + (blockIdx.z << 10);
    int Lp = ((Lf & 7) << 10) | (Lf >> 3);
    const int b  = Lp >> 10;
    const int hp = (Lp >> 5) & 31;
    const int wp = Lp & 31;
    const int h0 = hp << 3, w0 = wp << 3;

    // ---- stage x patch (f4 global loads) and w_in pairs ----
    #pragma unroll
    for (int k = 0; k < 2; ++k) {
        int i = tid + (k << 8);               // 0..511 float4s
        int c = i >> 4, rem = i & 15;
        int h = rem >> 1, half = rem & 1;
        const float4 v = *(const float4*)&x[((b * C_IN + c) * HH + h0 + h) * WW + w0 + (half << 2)];
        int base = c * 100 + half * 48 + h;
        ubuf[base]      = v.x;
        ubuf[base + 12] = v.y;
        ubuf[base + 24] = v.z;
        ubuf[base + 36] = v.w;
    }
    #pragma unroll
    for (int k = 0; k < 2; ++k) {
        int i = tid + (k << 8);               // 0..511 float4s over w_in
        int ci = i >> 3, c4 = (i & 7) << 2;
        const float4 v = *(const float4*)&w_in[ci * C_IN + c4];
        int col = ((ci & 31) << 1) | (ci >> 5);
        ubuf[3200 + (c4 + 0) * 66 + col] = v.x;
        ubuf[3200 + (c4 + 1) * 66 + col] = v.y;
        ubuf[3200 + (c4 + 2) * 66 + col] = v.z;
        ubuf[3200 + (c4 + 3) * 66 + col] = v.w;
    }
    __syncthreads();

    // ---- 1x1 conv: column w=l, 2 channels per thread ----
    float t0[8], t1[8];
    {
        const float bv0 = b_in[c2], bv1 = b_in[c2 + 32];
        #pragma unroll
        for (int h = 0; h < 8; ++h) { t0[h] = bv0; t1[h] = bv1; }
        #pragma unroll
        for (int c = 0; c < C_IN; ++c) {
            const float2 wv = *(const float2*)&ubuf[3200 + c * 66 + (c2 << 1)];
            const float4 xa = *(const float4*)&ubuf[c * 100 + l * 12];
            const float4 xb = *(const float4*)&ubuf[c * 100 + l * 12 + 4];
            float xv[8];
            xv[0] = xa.x; xv[1] = xa.y; xv[2] = xa.z; xv[3] = xa.w;
            xv[4] = xb.x; xv[5] = xb.y; xv[6] = xb.z; xv[7] = xb.w;
            #pragma unroll
            for (int h = 0; h < 8; ++h) {
                t0[h] = fmaf(wv.x, xv[h], t0[h]);
                t1[h] = fmaf(wv.y, xv[h], t1[h]);
            }
        }
    }

    // ---- row DFT over h (symmetry-reduced) ----
    float Ar_a[5], Ai_a[5], Ar_b[5], Ai_b[5];
    rdft8(t0, Ar_a, Ai_a);
    rdft8(t1, Ar_b, Ai_b);
    __syncthreads();            // xs/lw2 dead -> reuse for A
    wrA5(ubuf, c2,      l, Ar_a, Ai_a);
    wrA5(ubuf, c2 + 32, l, Ar_b, Ai_b);
    __syncthreads();

    // ---- column DFT + filter + gelu (role u = l) ----
    float gr_a[5], gi_a[5], gr_b[5], gi_b[5];
    colpass(ubuf, c2,      l, fft1, fft2, gr_a, gi_a);
    colpass(ubuf, c2 + 32, l, fft1, fft2, gr_b, gi_b);
    __syncthreads();            // A dead -> reuse for g
    {
        int gb = c2 * 100 + l * 12;
        *(float4*)&ubuf[gb]     = make_float4(gr_a[0], gi_a[0], gr_a[1], gi_a[1]);
        *(float4*)&ubuf[gb + 4] = make_float4(gr_a[2], gi_a[2], gr_a[3], gi_a[3]);
        *(float2*)&ubuf[gb + 8] = make_float2(gr_a[4], gi_a[4]);
        gb = (c2 + 32) * 100 + l * 12;
        *(float4*)&ubuf[gb]     = make_float4(gr_b[0], gi_b[0], gr_b[1], gi_b[1]);
        *(float4*)&ubuf[gb + 4] = make_float4(gr_b[2], gi_b[2], gr_b[3], gi_b[3]);
        *(float2*)&ubuf[gb + 8] = make_float2(gr_b[4], gi_b[4]);
    }
    __syncthreads();

    // ---- inverse (role h = l), rotation recurrence twiddles ----
    const float c1 = CT8d[l], s1 = ST8d[l];
    float o[8];
    const int pbase = (((b * C2C) * 1024) + hp * 32 + wp) << 6;   // word idx of patch (c2=0)
    invpass(&ubuf[c2 * 100], c1, s1, o);
    {
        float* zp = &z[pbase + (c2 << 16) + (l << 3)];
        *(float4*)&zp[0] = make_float4(o[0], o[1], o[2], o[3]);
        *(float4*)&zp[4] = make_float4(o[4], o[5], o[6], o[7]);
    }
    invpass(&ubuf[(c2 + 32) * 100], c1, s1, o);
    {
        float* zp = &z[pbase + ((c2 + 32) << 16) + (l << 3)];
        *(float4*)&zp[0] = make_float4(o[0], o[1], o[2], o[3]);
        *(float4*)&zp[4] = make_float4(o[4], o[5], o[6], o[7]);
    }
}

// ---------------------------------------------------------------------------
// K2: 7x7 depthwise conv (pad 3) + gelu + 1x1 conv out (64->32) + bias
// 16x16 tile per 256-thread WG; 16 chunks of 4 channels (one per wave).
// Conflict-free LDS: row stride 32 words + 16B-slot XOR swizzle (slot ^= row&7);
// dw lane roles (bx=lane>>4, oy=lane&15): each 8-lane group covers 8 consecutive
// rows at one x-slot -> 8 distinct bank-slots per b128.
// launch_bounds(256,4): do NOT raise (round-3 spill lesson).
// ---------------------------------------------------------------------------
__global__ __launch_bounds__(256, 4)
void k2_dwconv(const float* __restrict__ z, const float* __restrict__ w_dw,
               const float* __restrict__ b_dw, const float* __restrict__ w_out,
               const float* __restrict__ b_out, float* __restrict__ out)
{
    __shared__ __align__(16) float zs[4 * 22 * 32];   // 11264 B, swizzled slots
    __shared__ __align__(16) float gbuf[4 * 16 * 32]; // 8192 B, swizzled slots

    const int tid = threadIdx.x;

    // XCD-bijective swizzle (2048 blocks, one image per XCD)
    int L = blockIdx.x + (blockIdx.y << 4) + (blockIdx.z << 8);
    int Lp = ((L & 7) << 8) | (L >> 3);
    const int b  = Lp >> 8;
    const int ty = (Lp >> 4) & 15;
    const int tx = Lp & 15;
    const int x0g = tx << 4, y0g = ty << 4;

    // dw roles: wave = channel; lane -> (x-quad bx, output row oy)
    const int lane = tid & 63;
    const int wv   = tid >> 6;              // 0..3
    const int bx   = lane >> 4;             // 0..3 (x block, 4 wide)
    const int oy   = lane & 15;             // 0..15 output row

    // fold / output roles: thread = pixel
    const int ox = tid & 15, py = tid >> 4;

    float acc[32];
    #pragma unroll
    for (int c = 0; c < 32; ++c) acc[c] = b_out[c];

    for (int chunk = 0; chunk < 16; ++chunk) {
        const int cbase = chunk << 2;
        __syncthreads();   // protect zs/gbuf from previous iteration's readers

        // ---- stage 4 channels, 22-row x 24-col halo window (patch-local z) ----
        // window cols x0g-4 .. x0g+19 (4-aligned); rows y0g-3 .. y0g+18
        for (int i = tid; i < 528; i += 256) {     // 4 ch * 22 rows * 6 f4
            int c2l = i / 132;
            int r   = i - c2l * 132;
            int yy  = r / 6;
            int x4  = r - yy * 6;
            int gy = y0g - 3 + yy;
            int gx = x0g - 4 + (x4 << 2);
            float4 v = make_float4(0.f, 0.f, 0.f, 0.f);
            if ((unsigned)gy < HH && (unsigned)gx < WW) {
                const int hp = gy >> 3, wpp = gx >> 3;
                const int off = ((gy & 7) << 3) | (gx & 7);
                v = *(const float4*)&z[(((b * C2C + cbase + c2l) * 1024 + hp * 32 + wpp) << 6) + off];
            }
            *(float4*)&zs[c2l * 704 + yy * 32 + ((x4 ^ (yy & 7)) << 2)] = v;
        }
        __syncthreads();

        // ---- depthwise 7x7 for channel cbase+wv: 4 outputs per lane ----
        {
            const int c2u = __builtin_amdgcn_readfirstlane(cbase + wv);
            const float* wd = &w_dw[c2u * 49];        // uniform -> s_loads
            const float bd = b_dw[c2u];
            float a0 = bd, a1 = bd, a2 = bd, a3 = bd;
            const float* zch = &zs[wv * 704];
            #pragma unroll
            for (int ky = 0; ky < 7; ++ky) {
                const int row = oy + ky;
                const int rs = row & 7;
                const float* zr = &zch[row * 32];
                const float4 q0 = *(const float4*)&zr[((bx ^ rs) << 2)];
                const float4 q1 = *(const float4*)&zr[(((bx + 1) ^ rs) << 2)];
                const float4 q2 = *(const float4*)&zr[(((bx + 2) ^ rs) << 2)];
                const float fv[11] = {q0.x, q0.y, q0.z, q0.w, q1.x, q1.y, q1.z, q1.w,
                                      q2.x, q2.y, q2.z};
                #pragma unroll
                for (int kx = 0; kx < 7; ++kx) {
                    const float w = wd[ky * 7 + kx];
                    a0 = fmaf(w, fv[kx + 1], a0);
                    a1 = fmaf(w, fv[kx + 2], a1);
                    a2 = fmaf(w, fv[kx + 3], a2);
                    a3 = fmaf(w, fv[kx + 4], a3);
                }
            }
            *(float4*)&gbuf[wv * 512 + oy * 32 + ((bx ^ (oy & 7)) << 2)] =
                make_float4(gelu_f(a0), gelu_f(a1), gelu_f(a2), gelu_f(a3));
        }
        __syncthreads();

        // ---- fold chunk into 32 output-channel accumulators (uniform w_out) ----
        {
            const int sw = (((ox >> 2) ^ (py & 7)) << 2) | (ox & 3);
            #pragma unroll
            for (int cc = 0; cc < 4; ++cc) {
                const float gv = gbuf[cc * 512 + py * 32 + sw];
                const int c2i = cbase + cc;
                #pragma unroll
                for (int c = 0; c < 32; ++c)
                    acc[c] = fmaf(w_out[c * C2C + c2i], gv, acc[c]);
            }
        }
    }

    #pragma unroll
    for (int c = 0; c < 32; ++c)
        out[((b * C_IN + c) * HH + y0g + py) * WW + x0g + ox] = acc[c];
}

extern "C" void kernel_launch(void* const* d_in, const int* in_sizes, int n_in,
                              void* d_out, int out_size, void* d_ws, size_t ws_size,
                              hipStream_t stream) {
    const float* x     = (const float*)d_in[0];
    const float* w_in  = (const float*)d_in[1];
    const float* b_in  = (const float*)d_in[2];
    const float* fft1  = (const float*)d_in[3];
    const float* fft2  = (const float*)d_in[4];
    const float* w_dw  = (const float*)d_in[5];
    const float* b_dw  = (const float*)d_in[6];
    const float* w_out = (const float*)d_in[7];
    const float* b_out = (const float*)d_in[8];
    float* outp = (float*)d_out;
    float* z = (float*)d_ws;   // 128 MiB intermediate, patch-local [b][c2][hp][wp][8][8]

    dim3 g1(32, 32, 8);
    k1_spectral<<<g1, 256, 0, stream>>>(x, w_in, b_in, fft1, fft2, z);
    dim3 g2(16, 16, 8);
    k2_dwconv<<<g2, 256, 0, stream>>>(z, w_dw, b_dw, w_out, b_out, outp);
}

// Round 6
// 343.526 us; speedup vs baseline: 2.1803x; 1.1015x over previous
//
#include <hip/hip_runtime.h>
#include <math.h>

#define C_IN 32
#define C2C 64
#define HH 256
#define WW 256

#define R2 0.70710678118654752f

// Branchless gelu: erf via Abramowitz-Stegun 7.1.26 (|eps| <= 1.5e-7), hw rcp/exp.
__device__ __forceinline__ float gelu_f(float x) {
    float u = x * R2;
    float a = fabsf(u);
    float t = __builtin_amdgcn_rcpf(fmaf(0.3275911f, a, 1.0f));
    float p = t * fmaf(t, fmaf(t, fmaf(t, fmaf(t, 1.061405429f, -1.453152027f),
                                       1.421413741f), -0.284496736f), 0.254829592f);
    float e = __expf(-a * a);
    float er = fmaf(-p, e, 1.0f);
    er = copysignf(er, u);
    return 0.5f * x * (1.0f + er);
}

// cos/sin(2*pi*l/8) for the inverse-DFT rotation seed (2 loads per thread, once)
__device__ const float CT8d[8] = {1.0f, R2, 0.0f, -R2, -1.0f, -R2, 0.0f, R2};
__device__ const float ST8d[8] = {0.0f, R2, 1.0f, R2, 0.0f, -R2, -1.0f, -R2};

// 8-point real DFT over h with conjugate symmetry: outputs u=0..4 (Ai[0]=Ai[4]=0).
__device__ __forceinline__ void rdft8(const float t[8], float Ar[5], float Ai[5]) {
    float e0 = t[0] + t[4], e1 = t[1] + t[5], e2 = t[2] + t[6], e3 = t[3] + t[7];
    float s04 = t[0] - t[4], s26 = t[2] - t[6];
    float am = t[1] - t[3] - t[5] + t[7];
    float bm = t[1] + t[3] - t[5] - t[7];
    float e02 = e0 + e2, e13 = e1 + e3;
    Ar[0] = e02 + e13;
    Ar[4] = e02 - e13;
    Ar[2] = e0 - e2;
    Ai[2] = e3 - e1;
    float ma = R2 * am, mb = R2 * bm;
    Ar[1] = s04 + ma;
    Ar[3] = s04 - ma;
    Ai[1] = -s26 - mb;
    Ai[3] = s26 - mb;
    Ai[0] = 0.f;
    Ai[4] = 0.f;
}

// Store only spectral rows u=0..4 (conjugate symmetry); stride 44 per channel.
// Ar at c2*44 + u*8 + w ; Ai at 2816 + same.
__device__ __forceinline__ void wrA5(float* ubuf, int c2x, int l,
                                     const float Ar[5], const float Ai[5]) {
    float* pr = &ubuf[c2x * 44 + l];
    float* pi = &ubuf[2816 + c2x * 44 + l];
    pr[0]  = Ar[0];  pi[0]  = 0.f;
    pr[8]  = Ar[1];  pi[8]  = Ai[1];
    pr[16] = Ar[2];  pi[16] = Ai[2];
    pr[24] = Ar[3];  pi[24] = Ai[3];
    pr[32] = Ar[4];  pi[32] = 0.f;
}

// column DFT (v=0..4) + fft1 * -> gelu -> * fft2 ; row u=l via A[u]=conj(A[8-u])
__device__ __forceinline__ void colpass(const float* ubuf, int c2x, int l,
                                        const float* __restrict__ fft1,
                                        const float* __restrict__ fft2,
                                        float gr[5], float gi[5]) {
    constexpr float CT[8] = {1.0f, R2, 0.0f, -R2, -1.0f, -R2, 0.0f, R2};
    constexpr float ST[8] = {0.0f, R2, 1.0f, R2, 0.0f, -R2, -1.0f, -R2};
    const int row = (l <= 4) ? l : 8 - l;
    const float sgn = (l <= 4) ? 1.0f : -1.0f;
    float Ar2[8], Ai2[8];
    {
        const float4 r0 = *(const float4*)&ubuf[c2x * 44 + row * 8];
        const float4 r1 = *(const float4*)&ubuf[c2x * 44 + row * 8 + 4];
        const float4 i0 = *(const float4*)&ubuf[2816 + c2x * 44 + row * 8];
        const float4 i1 = *(const float4*)&ubuf[2816 + c2x * 44 + row * 8 + 4];
        Ar2[0] = r0.x; Ar2[1] = r0.y; Ar2[2] = r0.z; Ar2[3] = r0.w;
        Ar2[4] = r1.x; Ar2[5] = r1.y; Ar2[6] = r1.z; Ar2[7] = r1.w;
        Ai2[0] = sgn * i0.x; Ai2[1] = sgn * i0.y; Ai2[2] = sgn * i0.z; Ai2[3] = sgn * i0.w;
        Ai2[4] = sgn * i1.x; Ai2[5] = sgn * i1.y; Ai2[6] = sgn * i1.z; Ai2[7] = sgn * i1.w;
    }
    #pragma unroll
    for (int v = 0; v < 5; ++v) {
        float fr = 0.f, fi = 0.f;
        #pragma unroll
        for (int w = 0; w < 8; ++w) {
            const int k = (v * w) & 7;
            fr += Ar2[w] * CT[k] + Ai2[w] * ST[k];
            fi += Ai2[w] * CT[k] - Ar2[w] * ST[k];
        }
        const float s1 = fft1[(c2x * 8 + l) * 5 + v];
        const float s2 = fft2[(c2x * 8 + l) * 5 + v];
        gr[v] = gelu_f(fr * s1) * s2;
        gi[v] = gelu_f(fi * s1) * s2;
    }
}

// inverse: row-iDFT over u via rotation recurrence, then column-iDFT (hermitian over v)
__device__ __forceinline__ void invpass(const float* gtab, float c1, float s1, float o[8]) {
    constexpr float CT[8] = {1.0f, R2, 0.0f, -R2, -1.0f, -R2, 0.0f, R2};
    constexpr float ST[8] = {0.0f, R2, 1.0f, R2, 0.0f, -R2, -1.0f, -R2};
    float Rr[5] = {0.f, 0.f, 0.f, 0.f, 0.f};
    float Ri[5] = {0.f, 0.f, 0.f, 0.f, 0.f};
    float cu = 1.f, su = 0.f;
    #pragma unroll
    for (int u = 0; u < 8; ++u) {
        const float4 g0 = *(const float4*)&gtab[u * 12];
        const float4 g1 = *(const float4*)&gtab[u * 12 + 4];
        const float2 g2 = *(const float2*)&gtab[u * 12 + 8];
        Rr[0] += g0.x * cu - g0.y * su;  Ri[0] += g0.x * su + g0.y * cu;
        Rr[1] += g0.z * cu - g0.w * su;  Ri[1] += g0.z * su + g0.w * cu;
        Rr[2] += g1.x * cu - g1.y * su;  Ri[2] += g1.x * su + g1.y * cu;
        Rr[3] += g1.z * cu - g1.w * su;  Ri[3] += g1.z * su + g1.w * cu;
        Rr[4] += g2.x * cu - g2.y * su;  Ri[4] += g2.x * su + g2.y * cu;
        const float nc = cu * c1 - su * s1;
        su = cu * s1 + su * c1;
        cu = nc;
    }
    #pragma unroll
    for (int w = 0; w < 8; ++w) {
        float s = 0.f;
        #pragma unroll
        for (int v = 0; v < 5; ++v) {
            const float m = (v == 0 || v == 4) ? 1.0f : 2.0f;
            const int k = (v * w) & 7;
            s += m * (Rr[v] * CT[k] - Ri[v] * ST[k]);
        }
        o[w] = s * 0.015625f;
    }
}

// ---------------------------------------------------------------------------
// K1: 1x1 conv in (32->64) + per-patch rfft2*fft1 -> gelu -> *fft2 -> irfft2
// 256 threads per patch; thread = (c2 in 0..31 owning {c2, c2+32}, l = 0..7)
// z is written PATCH-LOCAL: [b][c2][hp][wp][h][w] -> 256B contiguous per patch.
// launch_bounds(256,4): VGPR cap 128. (256,6) capped at ~85 and spilled ->
// 1.35 GB scratch writes, 2.4x slowdown (round-3 post-mortem). UNCHANGED.
// ---------------------------------------------------------------------------
__global__ __launch_bounds__(256, 4)
void k1_spectral(const float* __restrict__ x, const float* __restrict__ w_in,
                 const float* __restrict__ b_in, const float* __restrict__ fft1,
                 const float* __restrict__ fft2, float* __restrict__ z)
{
    // union buffer (25600 B):
    //  phase0: xs[c][w][h] at c*100+w*12+h (0..3199); lw2 pairs at 3200+c*66+...
    //  phase1: Ar rows 0..4 at c2*44+u*8+w; Ai at 2816+... (0..5631)
    //  phase2: g at c2*100+u*12+2v (0..6399)
    __shared__ __align__(16) float ubuf[6400];

    const int tid = threadIdx.x;
    const int c2 = tid >> 3;
    const int l  = tid & 7;

    // XCD-bijective swizzle: each XCD gets one contiguous batch image (8192 blocks)
    int Lf = blockIdx.x + (blockIdx.y << 5) + (blockIdx.z << 10);
    int Lp = ((Lf & 7) << 10) | (Lf >> 3);
    const int b  = Lp >> 10;
    const int hp = (Lp >> 5) & 31;
    const int wp = Lp & 31;
    const int h0 = hp << 3, w0 = wp << 3;

    // ---- stage x patch (f4 global loads) and w_in pairs ----
    #pragma unroll
    for (int k = 0; k < 2; ++k) {
        int i = tid + (k << 8);               // 0..511 float4s
        int c = i >> 4, rem = i & 15;
        int h = rem >> 1, half = rem & 1;
        const float4 v = *(const float4*)&x[((b * C_IN + c) * HH + h0 + h) * WW + w0 + (half << 2)];
        int base = c * 100 + half * 48 + h;
        ubuf[base]      = v.x;
        ubuf[base + 12] = v.y;
        ubuf[base + 24] = v.z;
        ubuf[base + 36] = v.w;
    }
    #pragma unroll
    for (int k = 0; k < 2; ++k) {
        int i = tid + (k << 8);               // 0..511 float4s over w_in
        int ci = i >> 3, c4 = (i & 7) << 2;
        const float4 v = *(const float4*)&w_in[ci * C_IN + c4];
        int col = ((ci & 31) << 1) | (ci >> 5);
        ubuf[3200 + (c4 + 0) * 66 + col] = v.x;
        ubuf[3200 + (c4 + 1) * 66 + col] = v.y;
        ubuf[3200 + (c4 + 2) * 66 + col] = v.z;
        ubuf[3200 + (c4 + 3) * 66 + col] = v.w;
    }
    __syncthreads();

    // ---- 1x1 conv: column w=l, 2 channels per thread ----
    float t0[8], t1[8];
    {
        const float bv0 = b_in[c2], bv1 = b_in[c2 + 32];
        #pragma unroll
        for (int h = 0; h < 8; ++h) { t0[h] = bv0; t1[h] = bv1; }
        #pragma unroll
        for (int c = 0; c < C_IN; ++c) {
            const float2 wv = *(const float2*)&ubuf[3200 + c * 66 + (c2 << 1)];
            const float4 xa = *(const float4*)&ubuf[c * 100 + l * 12];
            const float4 xb = *(const float4*)&ubuf[c * 100 + l * 12 + 4];
            float xv[8];
            xv[0] = xa.x; xv[1] = xa.y; xv[2] = xa.z; xv[3] = xa.w;
            xv[4] = xb.x; xv[5] = xb.y; xv[6] = xb.z; xv[7] = xb.w;
            #pragma unroll
            for (int h = 0; h < 8; ++h) {
                t0[h] = fmaf(wv.x, xv[h], t0[h]);
                t1[h] = fmaf(wv.y, xv[h], t1[h]);
            }
        }
    }

    // ---- row DFT over h (symmetry-reduced) ----
    float Ar_a[5], Ai_a[5], Ar_b[5], Ai_b[5];
    rdft8(t0, Ar_a, Ai_a);
    rdft8(t1, Ar_b, Ai_b);
    __syncthreads();            // xs/lw2 dead -> reuse for A
    wrA5(ubuf, c2,      l, Ar_a, Ai_a);
    wrA5(ubuf, c2 + 32, l, Ar_b, Ai_b);
    __syncthreads();

    // ---- column DFT + filter + gelu (role u = l) ----
    float gr_a[5], gi_a[5], gr_b[5], gi_b[5];
    colpass(ubuf, c2,      l, fft1, fft2, gr_a, gi_a);
    colpass(ubuf, c2 + 32, l, fft1, fft2, gr_b, gi_b);
    __syncthreads();            // A dead -> reuse for g
    {
        int gb = c2 * 100 + l * 12;
        *(float4*)&ubuf[gb]     = make_float4(gr_a[0], gi_a[0], gr_a[1], gi_a[1]);
        *(float4*)&ubuf[gb + 4] = make_float4(gr_a[2], gi_a[2], gr_a[3], gi_a[3]);
        *(float2*)&ubuf[gb + 8] = make_float2(gr_a[4], gi_a[4]);
        gb = (c2 + 32) * 100 + l * 12;
        *(float4*)&ubuf[gb]     = make_float4(gr_b[0], gi_b[0], gr_b[1], gi_b[1]);
        *(float4*)&ubuf[gb + 4] = make_float4(gr_b[2], gi_b[2], gr_b[3], gi_b[3]);
        *(float2*)&ubuf[gb + 8] = make_float2(gr_b[4], gi_b[4]);
    }
    __syncthreads();

    // ---- inverse (role h = l), rotation recurrence twiddles ----
    const float c1 = CT8d[l], s1 = ST8d[l];
    float o[8];
    const int pbase = (((b * C2C) * 1024) + hp * 32 + wp) << 6;   // word idx of patch (c2=0)
    invpass(&ubuf[c2 * 100], c1, s1, o);
    {
        float* zp = &z[pbase + (c2 << 16) + (l << 3)];
        *(float4*)&zp[0] = make_float4(o[0], o[1], o[2], o[3]);
        *(float4*)&zp[4] = make_float4(o[4], o[5], o[6], o[7]);
    }
    invpass(&ubuf[(c2 + 32) * 100], c1, s1, o);
    {
        float* zp = &z[pbase + ((c2 + 32) << 16) + (l << 3)];
        *(float4*)&zp[0] = make_float4(o[0], o[1], o[2], o[3]);
        *(float4*)&zp[4] = make_float4(o[4], o[5], o[6], o[7]);
    }
}

// ---------------------------------------------------------------------------
// K2: 7x7 depthwise conv (pad 3) + gelu + 1x1 conv out (64->32) + bias
// 16x16 tile per 256-thread WG; 16 chunks of 4 channels (one per wave).
// T14 async-STAGE split: staging geometry is chunk-invariant -> precompute 3
// per-thread (src ptr, lds slot) pairs once; per chunk, write PREFETCHED
// registers to zs, then issue chunk+1's loads. vmcnt wait lands after the
// dw+fold compute -> HBM/L2 latency off the critical path.
// launch_bounds(256,4): do NOT raise (round-3 spill lesson).
// ---------------------------------------------------------------------------
__global__ __launch_bounds__(256, 4)
void k2_dwconv(const float* __restrict__ z, const float* __restrict__ w_dw,
               const float* __restrict__ b_dw, const float* __restrict__ w_out,
               const float* __restrict__ b_out, float* __restrict__ out)
{
    __shared__ __align__(16) float zs[4 * 22 * 32];   // 11264 B, swizzled slots
    __shared__ __align__(16) float gbuf[4 * 16 * 32]; // 8192 B, swizzled slots

    const int tid = threadIdx.x;

    // XCD-bijective swizzle (2048 blocks, one image per XCD)
    int L = blockIdx.x + (blockIdx.y << 4) + (blockIdx.z << 8);
    int Lp = ((L & 7) << 8) | (L >> 3);
    const int b  = Lp >> 8;
    const int ty = (Lp >> 4) & 15;
    const int tx = Lp & 15;
    const int x0g = tx << 4, y0g = ty << 4;

    // dw roles: wave = channel; lane -> (x-quad bx, output row oy)
    const int lane = tid & 63;
    const int wv   = tid >> 6;              // 0..3
    const int bx   = lane >> 4;             // 0..3 (x block, 4 wide)
    const int oy   = lane & 15;             // 0..15 output row

    // fold / output roles: thread = pixel
    const int ox = tid & 15, py = tid >> 4;

    // ---- precompute chunk-invariant staging slots (i = tid + k*256, i < 528) ----
    // slot k: source = z + ((b*C2C + c2l)<<16) + patch_inner ; dest = zs slot
    const float *zsrc0, *zsrc1, *zsrc2;
    int zdst0, zdst1, zdst2;
    bool zin0, zin1, zin2;                  // in-bounds (load vs zero)
    bool zact2;                             // slot 2 exists (tid < 16)
    {
        #define MK_SLOT(K, SRC, DST, INB, ACT)                                  \
        {                                                                        \
            const int i   = tid + (K << 8);                                      \
            const bool ac = (i < 528);                                           \
            const int c2l = i / 132;                                             \
            const int r   = i - c2l * 132;                                       \
            const int yy  = r / 6;                                               \
            const int x4  = r - yy * 6;                                          \
            const int gy  = y0g - 3 + yy;                                        \
            const int gx  = x0g - 4 + (x4 << 2);                                 \
            INB = ac && ((unsigned)gy < HH) && ((unsigned)gx < WW);              \
            const int hp  = (gy >> 3) & 31;                                      \
            const int wpp = (gx >> 3) & 31;                                      \
            const int off = ((gy & 7) << 3) | (gx & 7);                          \
            SRC = z + ((((b * C2C + (c2l & 3)) * 1024 + hp * 32 + wpp) << 6) + off); \
            DST = (c2l & 3) * 704 + (yy % 22) * 32 + ((x4 ^ (yy & 7)) << 2);     \
            ACT = ac;                                                            \
        }
        bool dummy0, dummy1;
        MK_SLOT(0, zsrc0, zdst0, zin0, dummy0)
        MK_SLOT(1, zsrc1, zdst1, zin1, dummy1)
        MK_SLOT(2, zsrc2, zdst2, zin2, zact2)
        (void)dummy0; (void)dummy1;
        #undef MK_SLOT
    }

    const float4 zero4 = make_float4(0.f, 0.f, 0.f, 0.f);

    // ---- prologue: prefetch chunk 0 ----
    float4 pf0 = zin0 ? *(const float4*)(zsrc0) : zero4;
    float4 pf1 = zin1 ? *(const float4*)(zsrc1) : zero4;
    float4 pf2 = zin2 ? *(const float4*)(zsrc2) : zero4;

    float acc[32];
    #pragma unroll
    for (int c = 0; c < 32; ++c) acc[c] = b_out[c];

    for (int chunk = 0; chunk < 16; ++chunk) {
        const int cbase = chunk << 2;
        __syncthreads();   // prev dw done reading zs; prev fold done reading gbuf

        // ---- commit prefetched chunk into zs ----
        *(float4*)&zs[zdst0] = pf0;
        *(float4*)&zs[zdst1] = pf1;
        if (zact2) *(float4*)&zs[zdst2] = pf2;

        // ---- issue next chunk's loads (latency hides under dw+fold) ----
        if (chunk < 15) {
            const int coff = (chunk + 1) << 18;        // 4 channels * 65536 floats
            pf0 = zin0 ? *(const float4*)(zsrc0 + coff) : zero4;
            pf1 = zin1 ? *(const float4*)(zsrc1 + coff) : zero4;
            pf2 = zin2 ? *(const float4*)(zsrc2 + coff) : zero4;
        }
        __syncthreads();   // zs ready

        // ---- depthwise 7x7 for channel cbase+wv: 4 outputs per lane ----
        {
            const int c2u = __builtin_amdgcn_readfirstlane(cbase + wv);
            const float* wd = &w_dw[c2u * 49];        // uniform -> s_loads
            const float bd = b_dw[c2u];
            float a0 = bd, a1 = bd, a2 = bd, a3 = bd;
            const float* zch = &zs[wv * 704];
            #pragma unroll
            for (int ky = 0; ky < 7; ++ky) {
                const int row = oy + ky;
                const int rs = row & 7;
                const float* zr = &zch[row * 32];
                const float4 q0 = *(const float4*)&zr[((bx ^ rs) << 2)];
                const float4 q1 = *(const float4*)&zr[(((bx + 1) ^ rs) << 2)];
                const float4 q2 = *(const float4*)&zr[(((bx + 2) ^ rs) << 2)];
                const float fv[11] = {q0.x, q0.y, q0.z, q0.w, q1.x, q1.y, q1.z, q1.w,
                                      q2.x, q2.y, q2.z};
                #pragma unroll
                for (int kx = 0; kx < 7; ++kx) {
                    const float w = wd[ky * 7 + kx];
                    a0 = fmaf(w, fv[kx + 1], a0);
                    a1 = fmaf(w, fv[kx + 2], a1);
                    a2 = fmaf(w, fv[kx + 3], a2);
                    a3 = fmaf(w, fv[kx + 4], a3);
                }
            }
            *(float4*)&gbuf[wv * 512 + oy * 32 + ((bx ^ (oy & 7)) << 2)] =
                make_float4(gelu_f(a0), gelu_f(a1), gelu_f(a2), gelu_f(a3));
        }
        __syncthreads();   // gbuf ready

        // ---- fold chunk into 32 output-channel accumulators (uniform w_out) ----
        {
            const int sw = (((ox >> 2) ^ (py & 7)) << 2) | (ox & 3);
            #pragma unroll
            for (int cc = 0; cc < 4; ++cc) {
                const float gv = gbuf[cc * 512 + py * 32 + sw];
                const int c2i = cbase + cc;
                #pragma unroll
                for (int c = 0; c < 32; ++c)
                    acc[c] = fmaf(w_out[c * C2C + c2i], gv, acc[c]);
            }
        }
    }

    #pragma unroll
    for (int c = 0; c < 32; ++c)
        out[((b * C_IN + c) * HH + y0g + py) * WW + x0g + ox] = acc[c];
}

extern "C" void kernel_launch(void* const* d_in, const int* in_sizes, int n_in,
                              void* d_out, int out_size, void* d_ws, size_t ws_size,
                              hipStream_t stream) {
    const float* x     = (const float*)d_in[0];
    const float* w_in  = (const float*)d_in[1];
    const float* b_in  = (const float*)d_in[2];
    const float* fft1  = (const float*)d_in[3];
    const float* fft2  = (const float*)d_in[4];
    const float* w_dw  = (const float*)d_in[5];
    const float* b_dw  = (const float*)d_in[6];
    const float* w_out = (const float*)d_in[7];
    const float* b_out = (const float*)d_in[8];
    float* outp = (float*)d_out;
    float* z = (float*)d_ws;   // 128 MiB intermediate, patch-local [b][c2][hp][wp][8][8]

    dim3 g1(32, 32, 8);
    k1_spectral<<<g1, 256, 0, stream>>>(x, w_in, b_in, fft1, fft2, z);
    dim3 g2(16, 16, 8);
    k2_dwconv<<<g2, 256, 0, stream>>>(z, w_dw, b_dw, w_out, b_out, outp);
}